// Round 2
// baseline (2779.941 us; speedup 1.0000x reference)
//
#include <hip/hip_runtime.h>

#define HDIM 256
#define KSTEPS 30
#define RPB 32            // rows per block
#define NTHR 512          // 8 waves

typedef _Float16 f16x8 __attribute__((ext_vector_type(8)));
typedef float f32x4 __attribute__((ext_vector_type(4)));

__device__ __forceinline__ f32x4 mfma16(f16x8 a, f16x8 b, f32x4 c) {
  return __builtin_amdgcn_mfma_f32_16x16x32_f16(a, b, c, 0, 0, 0);
}

__device__ __forceinline__ float sigm(float x) { return 1.0f / (1.0f + expf(-x)); }
__device__ __forceinline__ float softplusf(float x) {
  return fmaxf(x, 0.0f) + log1pf(expf(-fabsf(x)));
}

// swizzled byte offset for a [32][256] fp16 LDS tile (row stride 512B)
__device__ __forceinline__ int swz(int r, int c) {
  return r * 512 + ((c * 2) ^ ((r & 7) << 4));
}

__device__ __forceinline__ void wrsplit(char* hi, char* lo, int off, float v) {
  _Float16 h = (_Float16)v;
  *(_Float16*)(hi + off) = h;
  *(_Float16*)(lo + off) = (_Float16)(v - (float)h);
}
__device__ __forceinline__ float rdpair(const char* hi, const char* lo, int off) {
  return (float)*(const _Float16*)(hi + off) + (float)*(const _Float16*)(lo + off);
}

// ---------------- prep: f32->fp16 (hi/lo) conversions + teW ----------------
__global__ __launch_bounds__(256) void prep_kernel(
    const float* __restrict__ W1, const float* __restrict__ W2,
    const float* __restrict__ Wih0, const float* __restrict__ Whh0,
    const float* __restrict__ Wih1, const float* __restrict__ Whh1,
    const float* __restrict__ hf,
    _Float16* __restrict__ Whh0h, _Float16* __restrict__ Wih1h,
    _Float16* __restrict__ Whh1h,
    _Float16* __restrict__ W1h, _Float16* __restrict__ W1l,
    _Float16* __restrict__ W2h, _Float16* __restrict__ W2l,
    _Float16* __restrict__ Wih0hh, _Float16* __restrict__ Wih0hl,
    _Float16* __restrict__ hfh, _Float16* __restrict__ hfl,
    float* __restrict__ teW, int B)
{
  int e = blockIdx.x * 256 + threadIdx.x;
  if (e < 196608) { Whh0h[e] = (_Float16)Whh0[e]; return; } e -= 196608;
  if (e < 196608) { Wih1h[e] = (_Float16)Wih1[e]; return; } e -= 196608;
  if (e < 196608) { Whh1h[e] = (_Float16)Whh1[e]; return; } e -= 196608;
  if (e < 65536)  { float x = W1[e]; _Float16 h = (_Float16)x; W1h[e] = h; W1l[e] = (_Float16)(x - (float)h); return; } e -= 65536;
  if (e < 131072) { float x = W2[e]; _Float16 h = (_Float16)x; W2h[e] = h; W2l[e] = (_Float16)(x - (float)h); return; } e -= 131072;
  if (e < 196608) { int n = e >> 8, c = e & 255; float x = Wih0[n*291 + 35 + c]; _Float16 h = (_Float16)x; Wih0hh[e] = h; Wih0hl[e] = (_Float16)(x - (float)h); return; } e -= 196608;
  if (e < B*HDIM) { float x = hf[e]; _Float16 h = (_Float16)x; hfh[e] = h; hfl[e] = (_Float16)(x - (float)h); return; } e -= B*HDIM;
  if (e < KSTEPS*768) {
    int k = e / 768, n = e % 768;
    float pos = (float)k;
    const float fac = -9.210340371976184f / 31.0f;   // -ln(10000)/(TD-1)
    float acc = 0.0f;
    #pragma unroll
    for (int j = 0; j < 31; ++j) {
      int i = j >> 1;
      float ang = pos * expf((float)(2*i) * fac);
      float t = (j & 1) ? cosf(ang) : sinf(ang);
      acc += t * Wih0[n*291 + 3 + j];
    }
    acc += (pos / 30.0f) * Wih0[n*291 + 3 + 31];
    teW[e] = acc;
  }
}

// ---------------- Xc = hf @ Wih0[:,35:291].T + bih0  (B x 768 f32), 3-pass split ----------------
__global__ __launch_bounds__(64) void xc_kernel(
    const _Float16* __restrict__ hfh, const _Float16* __restrict__ hfl,
    const _Float16* __restrict__ Wh, const _Float16* __restrict__ Wl,
    const float* __restrict__ bih0, float* __restrict__ Xc)
{
  int l = threadIdx.x, l15 = l & 15, l4 = l >> 4;
  int bm = blockIdx.x;   // rows bm*16
  int bn = blockIdx.y;   // cols bn*64
  f32x4 acc[4];
  #pragma unroll
  for (int i = 0; i < 4; ++i) acc[i] = (f32x4){0,0,0,0};
  const _Float16* ah = hfh + (size_t)(bm*16 + l15)*256 + l4*8;
  const _Float16* al = hfl + (size_t)(bm*16 + l15)*256 + l4*8;
  #pragma unroll
  for (int kk = 0; kk < 8; ++kk) {
    f16x8 aH = *(const f16x8*)(ah + kk*32);
    f16x8 aL = *(const f16x8*)(al + kk*32);
    #pragma unroll
    for (int i = 0; i < 4; ++i) {
      size_t boff = (size_t)(bn*64 + i*16 + l15)*256 + l4*8 + kk*32;
      f16x8 bH = *(const f16x8*)(Wh + boff);
      f16x8 bL = *(const f16x8*)(Wl + boff);
      acc[i] = mfma16(aH, bH, acc[i]);
      acc[i] = mfma16(aL, bH, acc[i]);
      acc[i] = mfma16(aH, bL, acc[i]);
    }
  }
  #pragma unroll
  for (int i = 0; i < 4; ++i) {
    int n = bn*64 + i*16 + l15;
    float bb = bih0[n];
    #pragma unroll
    for (int j = 0; j < 4; ++j) {
      int r = bm*16 + l4*4 + j;
      Xc[(size_t)r*768 + n] = acc[i][j] + bb;
    }
  }
}

// ---------------- main persistent GRU kernel ----------------
// LDS layout (bytes)
#define OFF_H0    0        // 2 bufs: buf b hi at b*32768, lo at b*32768+16384
#define OFF_H1H   65536
#define OFF_H1L   81920
#define OFF_WS3   98304    // 768*3 f32 (Wih0[:,0:3])
#define OFF_BHH0  107520   // 768 f32
#define OFF_BI1   110592
#define OFF_BH1   113664
#define OFF_WOUT  116736
#define OFF_SPH   119808   // 32*8 f32
#define OFF_BOUT  120832
#define LDS_BYTES 120848

__global__ __launch_bounds__(NTHR, 2) void gru_main(
    const float* __restrict__ istate,
    const float* __restrict__ b1g, const float* __restrict__ b2g,
    const float* __restrict__ Wih0, const float* __restrict__ bhh0g,
    const float* __restrict__ bih1g, const float* __restrict__ bhh1g,
    const float* __restrict__ Woutg, const float* __restrict__ boutg,
    const _Float16* __restrict__ Whh0h, const _Float16* __restrict__ Wih1h,
    const _Float16* __restrict__ Whh1h,
    const _Float16* __restrict__ W1h, const _Float16* __restrict__ W1l,
    const _Float16* __restrict__ W2h, const _Float16* __restrict__ W2l,
    const _Float16* __restrict__ hfh, const _Float16* __restrict__ hfl,
    const float* __restrict__ teW, const float* __restrict__ Xc,
    float* __restrict__ out, int B)
{
  extern __shared__ char smem[];
  float* Ws3   = (float*)(smem + OFF_WS3);
  float* bhh0L = (float*)(smem + OFF_BHH0);
  float* bi1L  = (float*)(smem + OFF_BI1);
  float* bh1L  = (float*)(smem + OFF_BH1);
  float* WoutL = (float*)(smem + OFF_WOUT);
  float* sph   = (float*)(smem + OFF_SPH);
  float* boutL = (float*)(smem + OFF_BOUT);
  char* h1H = smem + OFF_H1H;
  char* h1L = smem + OFF_H1L;

  const int tid = threadIdx.x;
  const int w = tid >> 6;
  const int lane = tid & 63;
  const int l15 = lane & 15;
  const int l4 = lane >> 4;
  const int row0 = blockIdx.x * RPB;

  // ---- constants to LDS
  for (int i = tid; i < 2304; i += NTHR) Ws3[i] = Wih0[(i/3)*291 + (i%3)];
  for (int i = tid; i < 768; i += NTHR) {
    bhh0L[i] = bhh0g[i]; bi1L[i] = bih1g[i]; bh1L[i] = bhh1g[i]; WoutL[i] = Woutg[i];
  }
  if (tid < 3) boutL[tid] = boutg[tid];
  if (tid < RPB) {
    const float* is = istate + (size_t)(row0 + tid) * 3;
    float s0 = is[0], s1 = is[1], s2 = is[2];
    float* sp = sph + tid*8;
    sp[0] = s0; sp[1] = s1; sp[2] = s2;
    sp[3] = s0; sp[4] = s0; sp[5] = s0;   // pos_hist = initial_state[:,0] x3
  }

  // ---- h_init GEMM1: relu(hf @ W1.T + b1) -> buf0 (hi/lo)  [3-pass split]
  {
    char* mH = smem + OFF_H0;          // buf0 hi
    char* mL = smem + OFF_H0 + 16384;  // buf0 lo
    #pragma unroll
    for (int i = 0; i < 2; ++i) {
      int nt = w*2 + i;
      f32x4 acc0 = {0,0,0,0}, acc1 = {0,0,0,0};
      const _Float16* brh = W1h + (nt*16 + l15)*256 + l4*8;
      const _Float16* brl = W1l + (nt*16 + l15)*256 + l4*8;
      const _Float16* a0h = hfh + (size_t)(row0 + l15)*256 + l4*8;
      const _Float16* a0l = hfl + (size_t)(row0 + l15)*256 + l4*8;
      #pragma unroll
      for (int kk = 0; kk < 8; ++kk) {
        f16x8 bH = *(const f16x8*)(brh + kk*32);
        f16x8 bL = *(const f16x8*)(brl + kk*32);
        f16x8 aH0 = *(const f16x8*)(a0h + kk*32);
        f16x8 aL0 = *(const f16x8*)(a0l + kk*32);
        f16x8 aH1 = *(const f16x8*)(a0h + 16*256 + kk*32);
        f16x8 aL1 = *(const f16x8*)(a0l + 16*256 + kk*32);
        acc0 = mfma16(aH0, bH, acc0); acc0 = mfma16(aL0, bH, acc0); acc0 = mfma16(aH0, bL, acc0);
        acc1 = mfma16(aH1, bH, acc1); acc1 = mfma16(aL1, bH, acc1); acc1 = mfma16(aH1, bL, acc1);
      }
      int n = nt*16 + l15;
      float bb = b1g[n];
      #pragma unroll
      for (int mt = 0; mt < 2; ++mt) {
        f32x4 acc = mt ? acc1 : acc0;
        #pragma unroll
        for (int j = 0; j < 4; ++j) {
          int r = mt*16 + l4*4 + j;
          float v = fmaxf(acc[j] + bb, 0.0f);
          wrsplit(mH, mL, swz(r, n), v);
        }
      }
    }
  }
  __syncthreads();

  // ---- h_init GEMM2: tanh(hmid @ W2.T + b2) -> h0(buf1 hi/lo) / h1(hi/lo)
  {
    const char* mH = smem + OFF_H0;
    const char* mL = smem + OFF_H0 + 16384;
    char* o0H = smem + OFF_H0 + 32768;   // buf1 hi (h0 at k=0)
    char* o0L = smem + OFF_H0 + 49152;   // buf1 lo
    #pragma unroll
    for (int i = 0; i < 4; ++i) {
      int nt = w*4 + i;
      f32x4 acc0 = {0,0,0,0}, acc1 = {0,0,0,0};
      const _Float16* brh = W2h + (nt*16 + l15)*256 + l4*8;
      const _Float16* brl = W2l + (nt*16 + l15)*256 + l4*8;
      #pragma unroll
      for (int kk = 0; kk < 8; ++kk) {
        int kc = kk*32 + l4*8;
        f16x8 bH = *(const f16x8*)(brh + kk*32);
        f16x8 bL = *(const f16x8*)(brl + kk*32);
        f16x8 aH0 = *(const f16x8*)(mH + swz(l15, kc));
        f16x8 aL0 = *(const f16x8*)(mL + swz(l15, kc));
        f16x8 aH1 = *(const f16x8*)(mH + swz(16 + l15, kc));
        f16x8 aL1 = *(const f16x8*)(mL + swz(16 + l15, kc));
        acc0 = mfma16(aH0, bH, acc0); acc0 = mfma16(aL0, bH, acc0); acc0 = mfma16(aH0, bL, acc0);
        acc1 = mfma16(aH1, bH, acc1); acc1 = mfma16(aL1, bH, acc1); acc1 = mfma16(aH1, bL, acc1);
      }
      int n = nt*16 + l15;
      float bb = b2g[n];
      #pragma unroll
      for (int mt = 0; mt < 2; ++mt) {
        f32x4 acc = mt ? acc1 : acc0;
        #pragma unroll
        for (int j = 0; j < 4; ++j) {
          int r = mt*16 + l4*4 + j;
          float v = tanhf(acc[j] + bb);
          if (n < 256) wrsplit(o0H, o0L, swz(r, n), v);
          else         wrsplit(h1H, h1L, swz(r, n - 256), v);
        }
      }
    }
  }
  __syncthreads();

  const size_t outP = (size_t)B * KSTEPS;

  for (int k = 0; k < KSTEPS; ++k) {
    const char* hArH = smem + OFF_H0 + (((k & 1) ^ 1) << 15);
    const char* hArL = hArH + 16384;
    char* hAwH = smem + OFF_H0 + ((k & 1) << 15);
    char* hAwL = hAwH + 16384;
    const float* teWk = teW + k*768;

    // ---- Phase A: gh1 = h1 @ Whh1.T  (accumulators held until phase C)
    f32x4 ga[2][3][2];
    #pragma unroll
    for (int hti = 0; hti < 2; ++hti) {
      #pragma unroll
      for (int g = 0; g < 3; ++g) { ga[hti][g][0] = (f32x4){0,0,0,0}; ga[hti][g][1] = (f32x4){0,0,0,0}; }
      int ht = w + hti*8;
      const _Float16* br = Whh1h + (ht*16 + l15)*256 + l4*8;
      #pragma unroll
      for (int kk = 0; kk < 8; ++kk) {
        int kc = kk*32 + l4*8;
        f16x8 bR = *(const f16x8*)(br + kk*32);
        f16x8 bZ = *(const f16x8*)(br + 65536 + kk*32);
        f16x8 bN = *(const f16x8*)(br + 131072 + kk*32);
        f16x8 aH0 = *(const f16x8*)(h1H + swz(l15, kc));
        f16x8 aL0 = *(const f16x8*)(h1L + swz(l15, kc));
        f16x8 aH1 = *(const f16x8*)(h1H + swz(16 + l15, kc));
        f16x8 aL1 = *(const f16x8*)(h1L + swz(16 + l15, kc));
        ga[hti][0][0] = mfma16(aH0, bR, ga[hti][0][0]); ga[hti][0][0] = mfma16(aL0, bR, ga[hti][0][0]);
        ga[hti][0][1] = mfma16(aH1, bR, ga[hti][0][1]); ga[hti][0][1] = mfma16(aL1, bR, ga[hti][0][1]);
        ga[hti][1][0] = mfma16(aH0, bZ, ga[hti][1][0]); ga[hti][1][0] = mfma16(aL0, bZ, ga[hti][1][0]);
        ga[hti][1][1] = mfma16(aH1, bZ, ga[hti][1][1]); ga[hti][1][1] = mfma16(aL1, bZ, ga[hti][1][1]);
        ga[hti][2][0] = mfma16(aH0, bN, ga[hti][2][0]); ga[hti][2][0] = mfma16(aL0, bN, ga[hti][2][0]);
        ga[hti][2][1] = mfma16(aH1, bN, ga[hti][2][1]); ga[hti][2][1] = mfma16(aL1, bN, ga[hti][2][1]);
      }
    }

    // ---- Phase B: gh0 = h0 @ Whh0.T, fused GRU-0 epilogue -> h0n (hAw hi/lo)
    #pragma unroll
    for (int hti = 0; hti < 2; ++hti) {
      int ht = w + hti*8;
      f32x4 c[3][2];
      #pragma unroll
      for (int g = 0; g < 3; ++g) { c[g][0] = (f32x4){0,0,0,0}; c[g][1] = (f32x4){0,0,0,0}; }
      const _Float16* br = Whh0h + (ht*16 + l15)*256 + l4*8;
      #pragma unroll
      for (int kk = 0; kk < 8; ++kk) {
        int kc = kk*32 + l4*8;
        f16x8 bR = *(const f16x8*)(br + kk*32);
        f16x8 bZ = *(const f16x8*)(br + 65536 + kk*32);
        f16x8 bN = *(const f16x8*)(br + 131072 + kk*32);
        f16x8 aH0 = *(const f16x8*)(hArH + swz(l15, kc));
        f16x8 aL0 = *(const f16x8*)(hArL + swz(l15, kc));
        f16x8 aH1 = *(const f16x8*)(hArH + swz(16 + l15, kc));
        f16x8 aL1 = *(const f16x8*)(hArL + swz(16 + l15, kc));
        c[0][0] = mfma16(aH0, bR, c[0][0]); c[0][0] = mfma16(aL0, bR, c[0][0]);
        c[0][1] = mfma16(aH1, bR, c[0][1]); c[0][1] = mfma16(aL1, bR, c[0][1]);
        c[1][0] = mfma16(aH0, bZ, c[1][0]); c[1][0] = mfma16(aL0, bZ, c[1][0]);
        c[1][1] = mfma16(aH1, bZ, c[1][1]); c[1][1] = mfma16(aL1, bZ, c[1][1]);
        c[2][0] = mfma16(aH0, bN, c[2][0]); c[2][0] = mfma16(aL0, bN, c[2][0]);
        c[2][1] = mfma16(aH1, bN, c[2][1]); c[2][1] = mfma16(aL1, bN, c[2][1]);
      }
      int h = ht*16 + l15;
      float teR = teWk[h], teZ = teWk[256 + h], teN = teWk[512 + h];
      float wR0 = Ws3[h*3+0],       wR1 = Ws3[h*3+1],       wR2 = Ws3[h*3+2];
      float wZ0 = Ws3[(h+256)*3+0], wZ1 = Ws3[(h+256)*3+1], wZ2 = Ws3[(h+256)*3+2];
      float wN0 = Ws3[(h+512)*3+0], wN1 = Ws3[(h+512)*3+1], wN2 = Ws3[(h+512)*3+2];
      float bhR = bhh0L[h], bhZ = bhh0L[256 + h], bhN = bhh0L[512 + h];
      #pragma unroll
      for (int mt = 0; mt < 2; ++mt) {
        #pragma unroll
        for (int j = 0; j < 4; ++j) {
          int r = mt*16 + l4*4 + j;
          const float* xc = Xc + (size_t)(row0 + r)*768;
          const float* sp = sph + r*8;
          float s0 = sp[0], s1 = sp[1], s2 = sp[2];
          float giR = xc[h]       + teR + s0*wR0 + s1*wR1 + s2*wR2;
          float giZ = xc[256 + h] + teZ + s0*wZ0 + s1*wZ1 + s2*wZ2;
          float giN = xc[512 + h] + teN + s0*wN0 + s1*wN1 + s2*wN2;
          float rg = sigm(giR + c[0][mt][j] + bhR);
          float zg = sigm(giZ + c[1][mt][j] + bhZ);
          float ng = tanhf(giN + rg * (c[2][mt][j] + bhN));
          float hold = rdpair(hArH, hArL, swz(r, h));
          float hnew = (1.0f - zg) * ng + zg * hold;
          wrsplit(hAwH, hAwL, swz(r, h), hnew);
        }
      }
    }
    __syncthreads();

    // ---- Phase C: gi1 = h0n @ Wih1.T, fused GRU-1 epilogue (uses held ga) -> h1 (in place)
    #pragma unroll
    for (int hti = 0; hti < 2; ++hti) {
      int ht = w + hti*8;
      f32x4 c[3][2];
      #pragma unroll
      for (int g = 0; g < 3; ++g) { c[g][0] = (f32x4){0,0,0,0}; c[g][1] = (f32x4){0,0,0,0}; }
      const _Float16* br = Wih1h + (ht*16 + l15)*256 + l4*8;
      #pragma unroll
      for (int kk = 0; kk < 8; ++kk) {
        int kc = kk*32 + l4*8;
        f16x8 bR = *(const f16x8*)(br + kk*32);
        f16x8 bZ = *(const f16x8*)(br + 65536 + kk*32);
        f16x8 bN = *(const f16x8*)(br + 131072 + kk*32);
        f16x8 aH0 = *(const f16x8*)(hAwH + swz(l15, kc));
        f16x8 aL0 = *(const f16x8*)(hAwL + swz(l15, kc));
        f16x8 aH1 = *(const f16x8*)(hAwH + swz(16 + l15, kc));
        f16x8 aL1 = *(const f16x8*)(hAwL + swz(16 + l15, kc));
        c[0][0] = mfma16(aH0, bR, c[0][0]); c[0][0] = mfma16(aL0, bR, c[0][0]);
        c[0][1] = mfma16(aH1, bR, c[0][1]); c[0][1] = mfma16(aL1, bR, c[0][1]);
        c[1][0] = mfma16(aH0, bZ, c[1][0]); c[1][0] = mfma16(aL0, bZ, c[1][0]);
        c[1][1] = mfma16(aH1, bZ, c[1][1]); c[1][1] = mfma16(aL1, bZ, c[1][1]);
        c[2][0] = mfma16(aH0, bN, c[2][0]); c[2][0] = mfma16(aL0, bN, c[2][0]);
        c[2][1] = mfma16(aH1, bN, c[2][1]); c[2][1] = mfma16(aL1, bN, c[2][1]);
      }
      int h = ht*16 + l15;
      float biR = bi1L[h], biZ = bi1L[256+h], biN = bi1L[512+h];
      float bhR = bh1L[h], bhZ = bh1L[256+h], bhN = bh1L[512+h];
      #pragma unroll
      for (int mt = 0; mt < 2; ++mt) {
        #pragma unroll
        for (int j = 0; j < 4; ++j) {
          int r = mt*16 + l4*4 + j;
          float rg = sigm(c[0][mt][j] + biR + ga[hti][0][mt][j] + bhR);
          float zg = sigm(c[1][mt][j] + biZ + ga[hti][1][mt][j] + bhZ);
          float ng = tanhf(c[2][mt][j] + biN + rg * (ga[hti][2][mt][j] + bhN));
          float hold = rdpair(h1H, h1L, swz(r, h));
          float hnew = (1.0f - zg) * ng + zg * hold;
          wrsplit(h1H, h1L, swz(r, h), hnew);
        }
      }
    }
    __syncthreads();

    // ---- Phase D: qr = h1n @ Wout.T + bout, quantiles, state update
    {
      int r = tid >> 4, li = tid & 15;
      float q0 = 0.0f, q1 = 0.0f, q2 = 0.0f;
      #pragma unroll
      for (int i = 0; i < 16; ++i) {
        int h = li + i*16;
        float v = rdpair(h1H, h1L, swz(r, h));
        q0 += v * WoutL[h];
        q1 += v * WoutL[256 + h];
        q2 += v * WoutL[512 + h];
      }
      #pragma unroll
      for (int m = 1; m < 16; m <<= 1) {
        q0 += __shfl_xor(q0, m);
        q1 += __shfl_xor(q1, m);
        q2 += __shfl_xor(q2, m);
      }
      if (li == 0) {
        float qlo = q0 + boutL[0];
        float qm  = qlo + softplusf(q1 + boutL[1] - qlo);
        float qhi = qm  + softplusf(q2 + boutL[2] - qm);
        size_t b = row0 + r;
        out[b*KSTEPS + k]            = qlo;
        out[outP + b*KSTEPS + k]     = qm;
        out[2*outP + b*KSTEPS + k]   = qhi;
        float* sp = sph + r*8;
        float p1 = sp[4], p2 = sp[5];
        sp[0] = qm;
        sp[1] = (qm - p1) * 5.0f;                  // /(2*DT)
        sp[2] = (qm - 2.0f*p2 + p1) * 100.0f;      // /DT^2
        sp[3] = p1; sp[4] = p2; sp[5] = qm;
      }
    }
    __syncthreads();
  }
}

extern "C" void kernel_launch(void* const* d_in, const int* in_sizes, int n_in,
                              void* d_out, int out_size, void* d_ws, size_t ws_size,
                              hipStream_t stream) {
  const float* hf     = (const float*)d_in[0];
  const float* istate = (const float*)d_in[1];
  const float* W1     = (const float*)d_in[2];
  const float* b1     = (const float*)d_in[3];
  const float* W2     = (const float*)d_in[4];
  const float* b2     = (const float*)d_in[5];
  const float* Wih0   = (const float*)d_in[6];
  const float* Whh0   = (const float*)d_in[7];
  const float* bih0   = (const float*)d_in[8];
  const float* bhh0   = (const float*)d_in[9];
  const float* Wih1   = (const float*)d_in[10];
  const float* Whh1   = (const float*)d_in[11];
  const float* bih1   = (const float*)d_in[12];
  const float* bhh1   = (const float*)d_in[13];
  const float* Wout   = (const float*)d_in[14];
  const float* bout   = (const float*)d_in[15];
  float* out = (float*)d_out;
  const int B = in_sizes[0] / HDIM;   // 4096

  char* ws = (char*)d_ws;
  size_t o = 0;
  _Float16* Whh0h  = (_Float16*)(ws + o); o += 393216;
  _Float16* Wih1h  = (_Float16*)(ws + o); o += 393216;
  _Float16* Whh1h  = (_Float16*)(ws + o); o += 393216;
  _Float16* W1h    = (_Float16*)(ws + o); o += 131072;
  _Float16* W1l    = (_Float16*)(ws + o); o += 131072;
  _Float16* W2h    = (_Float16*)(ws + o); o += 262144;
  _Float16* W2l    = (_Float16*)(ws + o); o += 262144;
  _Float16* Wih0hh = (_Float16*)(ws + o); o += 393216;
  _Float16* Wih0hl = (_Float16*)(ws + o); o += 393216;
  _Float16* hfh    = (_Float16*)(ws + o); o += (size_t)B * HDIM * 2;
  _Float16* hfl    = (_Float16*)(ws + o); o += (size_t)B * HDIM * 2;
  float*    teW    = (float*)(ws + o);    o += (size_t)KSTEPS * 768 * 4;
  float*    Xc     = (float*)(ws + o);    o += (size_t)B * 768 * 4;
  if (ws_size < o) return;   // insufficient workspace -> fail loudly (poisoned out)

  const int prep_total = 196608*3 + 65536 + 131072 + 196608 + B*HDIM + KSTEPS*768;
  prep_kernel<<<dim3((prep_total + 255) / 256), dim3(256), 0, stream>>>(
      W1, W2, Wih0, Whh0, Wih1, Whh1, hf,
      Whh0h, Wih1h, Whh1h, W1h, W1l, W2h, W2l, Wih0hh, Wih0hl, hfh, hfl, teW, B);

  xc_kernel<<<dim3(B/16, 12), dim3(64), 0, stream>>>(hfh, hfl, Wih0hh, Wih0hl, bih0, Xc);

  hipFuncSetAttribute((const void*)gru_main,
                      hipFuncAttributeMaxDynamicSharedMemorySize, LDS_BYTES);
  gru_main<<<dim3(B/RPB), dim3(NTHR), LDS_BYTES, stream>>>(
      istate, b1, b2, Wih0, bhh0, bih1, bhh1, Wout, bout,
      Whh0h, Wih1h, Whh1h, W1h, W1l, W2h, W2l, hfh, hfl, teW, Xc, out, B);
}